// Round 6
// baseline (133.690 us; speedup 1.0000x reference)
//
#include <hip/hip_runtime.h>
#include <math.h>

#define BATCH 512

__device__ __forceinline__ float elu1(float v) {
    return v > 0.f ? v : expm1f(v);
}

// ============ Kernel 1: conv1 (9-dir stencil, 1->32) + ELU + 2x2 pool ============
__global__ __launch_bounds__(256) void k1_conv1_pool(
    const float* __restrict__ x, const float* __restrict__ W1,
    const float* __restrict__ root1, const float* __restrict__ b1,
    float* __restrict__ p1) {
    __shared__ float xs[900];            // [30][30] zero-padded image
    __shared__ float w1s[8 * 32 + 64];
    const int b = blockIdx.x;
    const int t = threadIdx.x;

    for (int l = t; l < 900; l += 256) xs[l] = 0.f;
    {
        int d = t >> 5, c = t & 31;
        int e = d + (d >= 4 ? 1 : 0);
        int dy = e / 3 - 1, dx = e % 3 - 1;
        int widx = 2 * (dx + 1) + 10 * (dy + 1);
        w1s[t] = W1[widx * 32 + c];
        if (t < 32) { w1s[256 + t] = root1[t]; w1s[288 + t] = b1[t]; }
    }
    __syncthreads();
    const float* xb = x + (size_t)b * 784;
    for (int l = t; l < 784; l += 256) {
        int y = l / 28, xx = l % 28;
        xs[(y + 1) * 30 + xx + 1] = xb[l];
    }
    __syncthreads();

    if (t >= 196) return;
    int py = t / 14, px = t % 14;
    int xbse[4];
    float xc[4], inv[4];
    #pragma unroll
    for (int p = 0; p < 4; ++p) {
        int sy = p >> 1, sx = p & 1;
        int y = 2 * py + sy, xx = 2 * px + sx;
        xbse[p] = (y + 1) * 30 + xx + 1;
        xc[p] = xs[xbse[p]];
        int nvy = 3 - (y == 0) - (y == 27);
        int nvx = 3 - (xx == 0) - (xx == 27);
        inv[p] = 1.f / (float)(nvy * nvx - 1);
    }
    const float4* w4 = (const float4*)w1s;
    float* outp = p1 + ((size_t)b * 196 + t) * 32;

    #pragma unroll
    for (int h = 0; h < 2; ++h) {
        float4 acc[4][4];
        #pragma unroll
        for (int p = 0; p < 4; ++p)
            #pragma unroll
            for (int q = 0; q < 4; ++q) acc[p][q] = make_float4(0.f, 0.f, 0.f, 0.f);
        #pragma unroll
        for (int d = 0; d < 8; ++d) {
            int e = d + (d >= 4 ? 1 : 0);
            int od = (e / 3 - 1) * 30 + (e % 3 - 1);
            float4 w0 = w4[d * 8 + h * 4 + 0];
            float4 w1 = w4[d * 8 + h * 4 + 1];
            float4 w2 = w4[d * 8 + h * 4 + 2];
            float4 w3 = w4[d * 8 + h * 4 + 3];
            #pragma unroll
            for (int p = 0; p < 4; ++p) {
                float xv = xs[xbse[p] + od];
                acc[p][0].x += xv * w0.x; acc[p][0].y += xv * w0.y; acc[p][0].z += xv * w0.z; acc[p][0].w += xv * w0.w;
                acc[p][1].x += xv * w1.x; acc[p][1].y += xv * w1.y; acc[p][1].z += xv * w1.z; acc[p][1].w += xv * w1.w;
                acc[p][2].x += xv * w2.x; acc[p][2].y += xv * w2.y; acc[p][2].z += xv * w2.z; acc[p][2].w += xv * w2.w;
                acc[p][3].x += xv * w3.x; acc[p][3].y += xv * w3.y; acc[p][3].z += xv * w3.z; acc[p][3].w += xv * w3.w;
            }
        }
        #pragma unroll
        for (int q = 0; q < 4; ++q) {
            float4 rt = w4[64 + h * 4 + q];
            float4 bs = w4[72 + h * 4 + q];
            float4 m = make_float4(-1e30f, -1e30f, -1e30f, -1e30f);
            #pragma unroll
            for (int p = 0; p < 4; ++p) {
                float4 v;
                v.x = elu1(acc[p][q].x * inv[p] + xc[p] * rt.x + bs.x);
                v.y = elu1(acc[p][q].y * inv[p] + xc[p] * rt.y + bs.y);
                v.z = elu1(acc[p][q].z * inv[p] + xc[p] * rt.z + bs.z);
                v.w = elu1(acc[p][q].w * inv[p] + xc[p] * rt.w + bs.w);
                m.x = fmaxf(m.x, v.x); m.y = fmaxf(m.y, v.y);
                m.z = fmaxf(m.z, v.z); m.w = fmaxf(m.w, v.w);
            }
            *(float4*)(outp + h * 16 + q * 4) = m;
        }
    }
}

// ============ Kernel 2: conv2 (9-dir, 32->64) + ELU + 2x2 pool ============
// Round-3 mapping and d-outer/i-inner summation order (bit-exact vs np).
// New: xs node stride 36 (16B-aligned), i read as float4 per (d,pos,i4),
// i-block XOR-swizzled by padded row to spread banks. W dbuf as round 5.
__global__ __launch_bounds__(256) void k2_conv2_pool(
    const float* __restrict__ p1, const float* __restrict__ W2,
    const float* __restrict__ root2, const float* __restrict__ b2,
    float* __restrict__ p2) {
    __shared__ float xs[9216];         // 256 nodes * 36
    __shared__ float wb[2][2176];      // [32][68] per direction, padded
    const int b = blockIdx.x;
    const int t = threadIdx.x;
    const int cell = t >> 2, cg = t & 3;
    const int coff = cg * 16 + (cg >> 1) * 4;   // 0,16,36,52 floats

    // stage dir-0 weights (widx 0 is first matrix of W2), padded-scatter
    {
        const float4* s4 = (const float4*)W2;
        float4* w4p = (float4*)wb[0];
        #pragma unroll
        for (int j = 0; j < 2; ++j) {
            int l = t + j * 256;
            int i = l >> 4, c4 = l & 15, g = c4 >> 2, q = c4 & 3;
            w4p[i * 17 + g * 4 + (g >> 1) + q] = s4[l];
        }
    }
    // zero xs
    for (int l = t; l < 9216; l += 256) xs[l] = 0.f;
    __syncthreads();
    // interior fill: p1 is [b][196][32] node-major; swizzled i-block scatter
    {
        const float* src = p1 + (size_t)b * 6272;
        for (int l = t; l < 6272; l += 256) {
            int node = l >> 5, i = l & 31;
            int y = node / 14, xx = node - y * 14;
            int np = (y + 1) * 16 + xx + 1;
            xs[np * 36 + 4 * ((i >> 2) ^ ((np >> 4) & 7)) + (i & 3)] = src[l];
        }
    }
    __syncthreads();

    const int ccell = (cell < 49) ? cell : 48;
    const int py = ccell / 7, px = ccell - py * 7;
    int npv[4];
    float inv[4];
    #pragma unroll
    for (int p = 0; p < 4; ++p) {
        int sy = p >> 1, sx = p & 1;
        int y = 2 * py + sy, xx = 2 * px + sx;
        npv[p] = (y + 1) * 16 + xx + 1;
        int nvy = 3 - (y == 0) - (y == 13);
        int nvx = 3 - (xx == 0) - (xx == 13);
        inv[p] = 1.f / (float)(nvy * nvx - 1);
    }

    float4 acc[4][4];
    #pragma unroll
    for (int p = 0; p < 4; ++p)
        #pragma unroll
        for (int q = 0; q < 4; ++q) acc[p][q] = make_float4(0.f, 0.f, 0.f, 0.f);

    for (int d = 0; d < 9; ++d) {
        // prefetch next direction's weights into registers
        float4 pf0, pf1;
        if (d < 8) {
            int nd = d + 1;
            const float* nsrc;
            if (nd == 8) nsrc = root2;
            else {
                int e = nd + (nd >= 4 ? 1 : 0);
                int dy = e / 3 - 1, dx = e % 3 - 1;
                nsrc = W2 + (size_t)(2 * (dx + 1) + 10 * (dy + 1)) * 2048;
            }
            pf0 = ((const float4*)nsrc)[t];
            pf1 = ((const float4*)nsrc)[t + 256];
        }
        if (d == 8) {
            // scale neighbor sums by 1/deg before root contribution (reference order)
            #pragma unroll
            for (int p = 0; p < 4; ++p) {
                acc[p][0].x *= inv[p]; acc[p][0].y *= inv[p]; acc[p][0].z *= inv[p]; acc[p][0].w *= inv[p];
                acc[p][1].x *= inv[p]; acc[p][1].y *= inv[p]; acc[p][1].z *= inv[p]; acc[p][1].w *= inv[p];
                acc[p][2].x *= inv[p]; acc[p][2].y *= inv[p]; acc[p][2].z *= inv[p]; acc[p][2].w *= inv[p];
                acc[p][3].x *= inv[p]; acc[p][3].y *= inv[p]; acc[p][3].z *= inv[p]; acc[p][3].w *= inv[p];
            }
        }
        int dnode = 0;
        if (d < 8) {
            int e = d + (d >= 4 ? 1 : 0);
            dnode = (e / 3 - 1) * 16 + (e % 3 - 1);
        }
        // per-pos neighbor base + swizzle key
        int xb0, xb1, xb2, xb3, sz0, sz1, sz2, sz3;
        {
            int n0 = npv[0] + dnode, n1 = npv[1] + dnode,
                n2 = npv[2] + dnode, n3 = npv[3] + dnode;
            xb0 = n0 * 36; sz0 = (n0 >> 4) & 7;
            xb1 = n1 * 36; sz1 = (n1 >> 4) & 7;
            xb2 = n2 * 36; sz2 = (n2 >> 4) & 7;
            xb3 = n3 * 36; sz3 = (n3 >> 4) & 7;
        }
        const float* wcur = wb[d & 1] + coff;
        #pragma unroll 2
        for (int i4 = 0; i4 < 8; ++i4) {
            float4 xv0 = *(const float4*)(xs + xb0 + 4 * (i4 ^ sz0));
            float4 xv1 = *(const float4*)(xs + xb1 + 4 * (i4 ^ sz1));
            float4 xv2 = *(const float4*)(xs + xb2 + 4 * (i4 ^ sz2));
            float4 xv3 = *(const float4*)(xs + xb3 + 4 * (i4 ^ sz3));
            float xa0[4] = {xv0.x, xv0.y, xv0.z, xv0.w};
            float xa1[4] = {xv1.x, xv1.y, xv1.z, xv1.w};
            float xa2[4] = {xv2.x, xv2.y, xv2.z, xv2.w};
            float xa3[4] = {xv3.x, xv3.y, xv3.z, xv3.w};
            #pragma unroll
            for (int ii = 0; ii < 4; ++ii) {
                const float* wrow = wcur + (i4 * 4 + ii) * 68;
                float4 w0 = *(const float4*)(wrow + 0);
                float4 w1 = *(const float4*)(wrow + 4);
                float4 w2 = *(const float4*)(wrow + 8);
                float4 w3 = *(const float4*)(wrow + 12);
                float x0 = xa0[ii], x1 = xa1[ii], x2 = xa2[ii], x3 = xa3[ii];
                acc[0][0].x += x0 * w0.x; acc[0][0].y += x0 * w0.y; acc[0][0].z += x0 * w0.z; acc[0][0].w += x0 * w0.w;
                acc[0][1].x += x0 * w1.x; acc[0][1].y += x0 * w1.y; acc[0][1].z += x0 * w1.z; acc[0][1].w += x0 * w1.w;
                acc[0][2].x += x0 * w2.x; acc[0][2].y += x0 * w2.y; acc[0][2].z += x0 * w2.z; acc[0][2].w += x0 * w2.w;
                acc[0][3].x += x0 * w3.x; acc[0][3].y += x0 * w3.y; acc[0][3].z += x0 * w3.z; acc[0][3].w += x0 * w3.w;
                acc[1][0].x += x1 * w0.x; acc[1][0].y += x1 * w0.y; acc[1][0].z += x1 * w0.z; acc[1][0].w += x1 * w0.w;
                acc[1][1].x += x1 * w1.x; acc[1][1].y += x1 * w1.y; acc[1][1].z += x1 * w1.z; acc[1][1].w += x1 * w1.w;
                acc[1][2].x += x1 * w2.x; acc[1][2].y += x1 * w2.y; acc[1][2].z += x1 * w2.z; acc[1][2].w += x1 * w2.w;
                acc[1][3].x += x1 * w3.x; acc[1][3].y += x1 * w3.y; acc[1][3].z += x1 * w3.z; acc[1][3].w += x1 * w3.w;
                acc[2][0].x += x2 * w0.x; acc[2][0].y += x2 * w0.y; acc[2][0].z += x2 * w0.z; acc[2][0].w += x2 * w0.w;
                acc[2][1].x += x2 * w1.x; acc[2][1].y += x2 * w1.y; acc[2][1].z += x2 * w1.z; acc[2][1].w += x2 * w1.w;
                acc[2][2].x += x2 * w2.x; acc[2][2].y += x2 * w2.y; acc[2][2].z += x2 * w2.z; acc[2][2].w += x2 * w2.w;
                acc[2][3].x += x2 * w3.x; acc[2][3].y += x2 * w3.y; acc[2][3].z += x2 * w3.z; acc[2][3].w += x2 * w3.w;
                acc[3][0].x += x3 * w0.x; acc[3][0].y += x3 * w0.y; acc[3][0].z += x3 * w0.z; acc[3][0].w += x3 * w0.w;
                acc[3][1].x += x3 * w1.x; acc[3][1].y += x3 * w1.y; acc[3][1].z += x3 * w1.z; acc[3][1].w += x3 * w1.w;
                acc[3][2].x += x3 * w2.x; acc[3][2].y += x3 * w2.y; acc[3][2].z += x3 * w2.z; acc[3][2].w += x3 * w2.w;
                acc[3][3].x += x3 * w3.x; acc[3][3].y += x3 * w3.y; acc[3][3].z += x3 * w3.z; acc[3][3].w += x3 * w3.w;
            }
        }
        if (d < 8) {
            float4* wn = (float4*)wb[(d + 1) & 1];
            #pragma unroll
            for (int j = 0; j < 2; ++j) {
                int l = t + j * 256;
                int i = l >> 4, c4 = l & 15, g = c4 >> 2, q = c4 & 3;
                wn[i * 17 + g * 4 + (g >> 1) + q] = (j == 0) ? pf0 : pf1;
            }
        }
        __syncthreads();
    }

    if (cell < 49) {
        float* outp = p2 + (size_t)b * 3136 + cell * 64 + cg * 16;
        #pragma unroll
        for (int q = 0; q < 4; ++q) {
            float4 bs = *(const float4*)(b2 + cg * 16 + q * 4);
            float4 m = make_float4(-1e30f, -1e30f, -1e30f, -1e30f);
            #pragma unroll
            for (int p = 0; p < 4; ++p) {
                float4 v;
                v.x = elu1(acc[p][q].x + bs.x);
                v.y = elu1(acc[p][q].y + bs.y);
                v.z = elu1(acc[p][q].z + bs.z);
                v.w = elu1(acc[p][q].w + bs.w);
                m.x = fmaxf(m.x, v.x); m.y = fmaxf(m.y, v.y);
                m.z = fmaxf(m.z, v.z); m.w = fmaxf(m.w, v.w);
            }
            *(float4*)(outp + q * 4) = m;
        }
    }
}

// ============ Kernel 3a: fc1 split-K GEMM, 128x128 tile, 8x8/thread, BK=16 ============
__global__ __launch_bounds__(256) void k3a_fc1(
    const float* __restrict__ A, const float* __restrict__ B,
    float* __restrict__ part, int kchunk) {
    __shared__ float As[2][16][128];
    __shared__ float Bs[2][16][132];
    const int t = threadIdx.x;
    const int tx = t & 15, ty = t >> 4;
    const int n0 = blockIdx.x * 128, m0 = blockIdx.y * 128;
    const int k0 = blockIdx.z * kchunk;
    const int steps = kchunk >> 4;

    const int sm = t & 127, skh = t >> 7;     // A staging
    const int sk = t >> 4, snq = t & 15;      // B staging
    const float* Ap = A + (size_t)(m0 + sm) * 3136 + k0 + skh * 8;
    const float* Bp = B + (size_t)(k0 + sk) * 512 + n0 + snq * 8;

    {
        float4 a0 = *(const float4*)Ap;
        float4 a1 = *(const float4*)(Ap + 4);
        float4 b0 = *(const float4*)Bp;
        float4 b1 = *(const float4*)(Bp + 4);
        As[0][skh * 8 + 0][sm] = a0.x; As[0][skh * 8 + 1][sm] = a0.y;
        As[0][skh * 8 + 2][sm] = a0.z; As[0][skh * 8 + 3][sm] = a0.w;
        As[0][skh * 8 + 4][sm] = a1.x; As[0][skh * 8 + 5][sm] = a1.y;
        As[0][skh * 8 + 6][sm] = a1.z; As[0][skh * 8 + 7][sm] = a1.w;
        *(float4*)&Bs[0][sk][snq * 8] = b0;
        *(float4*)&Bs[0][sk][snq * 8 + 4] = b1;
    }
    __syncthreads();

    float acc[8][8];
    #pragma unroll
    for (int r = 0; r < 8; ++r)
        #pragma unroll
        for (int c = 0; c < 8; ++c) acc[r][c] = 0.f;

    for (int s = 0; s < steps; ++s) {
        float4 a0, a1, b0, b1;
        if (s + 1 < steps) {
            a0 = *(const float4*)(Ap + (s + 1) * 16);
            a1 = *(const float4*)(Ap + (s + 1) * 16 + 4);
            b0 = *(const float4*)(Bp + (size_t)(s + 1) * 16 * 512);
            b1 = *(const float4*)(Bp + (size_t)(s + 1) * 16 * 512 + 4);
        }
        const int cur = s & 1;
        #pragma unroll
        for (int k = 0; k < 16; ++k) {
            float4 av0 = *(const float4*)&As[cur][k][ty * 8];
            float4 av1 = *(const float4*)&As[cur][k][ty * 8 + 4];
            float4 bv0 = *(const float4*)&Bs[cur][k][tx * 4];
            float4 bv1 = *(const float4*)&Bs[cur][k][64 + tx * 4];
            float ar[8] = {av0.x, av0.y, av0.z, av0.w, av1.x, av1.y, av1.z, av1.w};
            #pragma unroll
            for (int r = 0; r < 8; ++r) {
                acc[r][0] += ar[r] * bv0.x; acc[r][1] += ar[r] * bv0.y;
                acc[r][2] += ar[r] * bv0.z; acc[r][3] += ar[r] * bv0.w;
                acc[r][4] += ar[r] * bv1.x; acc[r][5] += ar[r] * bv1.y;
                acc[r][6] += ar[r] * bv1.z; acc[r][7] += ar[r] * bv1.w;
            }
        }
        if (s + 1 < steps) {
            const int nxt = cur ^ 1;
            As[nxt][skh * 8 + 0][sm] = a0.x; As[nxt][skh * 8 + 1][sm] = a0.y;
            As[nxt][skh * 8 + 2][sm] = a0.z; As[nxt][skh * 8 + 3][sm] = a0.w;
            As[nxt][skh * 8 + 4][sm] = a1.x; As[nxt][skh * 8 + 5][sm] = a1.y;
            As[nxt][skh * 8 + 6][sm] = a1.z; As[nxt][skh * 8 + 7][sm] = a1.w;
            *(float4*)&Bs[nxt][sk][snq * 8] = b0;
            *(float4*)&Bs[nxt][sk][snq * 8 + 4] = b1;
        }
        __syncthreads();
    }

    float* pbase = part + ((size_t)blockIdx.z * 512 + m0 + ty * 8) * 512 + n0;
    #pragma unroll
    for (int r = 0; r < 8; ++r) {
        float4 o0 = make_float4(acc[r][0], acc[r][1], acc[r][2], acc[r][3]);
        float4 o1 = make_float4(acc[r][4], acc[r][5], acc[r][6], acc[r][7]);
        *(float4*)(pbase + (size_t)r * 512 + tx * 4) = o0;
        *(float4*)(pbase + (size_t)r * 512 + 64 + tx * 4) = o1;
    }
}

// ============ Kernel 34: reduce fc1 partials + bias + ELU, then fc2 + ELU + lsm ============
__global__ __launch_bounds__(256) void k34_reduce_fc2_lsm(
    const float* __restrict__ part, const float* __restrict__ fc1b,
    const float* __restrict__ w, const float* __restrict__ fc2b,
    float* __restrict__ out, int KZ) {
    __shared__ float red[4][10];
    const int b = blockIdx.x, t = threadIdx.x;

    float a0 = fc1b[t], a1 = fc1b[t + 256];
    for (int kz = 0; kz < KZ; ++kz) {
        const float* pr = part + ((size_t)kz * 512 + b) * 512;
        a0 += pr[t]; a1 += pr[t + 256];
    }
    a0 = elu1(a0); a1 = elu1(a1);

    float acc[10];
    #pragma unroll
    for (int o = 0; o < 10; ++o)
        acc[o] = a0 * w[t * 10 + o] + a1 * w[(t + 256) * 10 + o];
    #pragma unroll
    for (int s = 32; s; s >>= 1)
        #pragma unroll
        for (int o = 0; o < 10; ++o) acc[o] += __shfl_xor(acc[o], s, 64);
    if ((t & 63) == 0) {
        #pragma unroll
        for (int o = 0; o < 10; ++o) red[t >> 6][o] = acc[o];
    }
    __syncthreads();
    if (t == 0) {
        float v[10], m = -1e30f;
        #pragma unroll
        for (int o = 0; o < 10; ++o) {
            float s = red[0][o] + red[1][o] + red[2][o] + red[3][o] + fc2b[o];
            v[o] = elu1(s);
            m = fmaxf(m, v[o]);
        }
        float ssum = 0.f;
        #pragma unroll
        for (int o = 0; o < 10; ++o) ssum += expf(v[o] - m);
        float lse = m + logf(ssum);
        #pragma unroll
        for (int o = 0; o < 10; ++o) out[(size_t)b * 10 + o] = v[o] - lse;
    }
}

extern "C" void kernel_launch(void* const* d_in, const int* in_sizes, int n_in,
                              void* d_out, int out_size, void* d_ws, size_t ws_size,
                              hipStream_t stream) {
    const float* x     = (const float*)d_in[0];
    const float* W1    = (const float*)d_in[3];
    const float* root1 = (const float*)d_in[4];
    const float* b1v   = (const float*)d_in[5];
    const float* W2    = (const float*)d_in[6];
    const float* root2 = (const float*)d_in[7];
    const float* b2v   = (const float*)d_in[8];
    const float* fc1w  = (const float*)d_in[9];
    const float* fc1b  = (const float*)d_in[10];
    const float* fc2w  = (const float*)d_in[11];
    const float* fc2b  = (const float*)d_in[12];

    float* ws = (float*)d_ws;
    float* p1 = ws;                                   // 3,211,264 f
    float* p2 = p1 + (size_t)BATCH * 196 * 32;        // 1,605,632 f
    float* tail = p2 + (size_t)BATCH * 49 * 64;

    const size_t base_f = 3211264u + 1605632u;
    int KZ; float* part;
    if (ws_size >= (base_f + 28u * 262144u) * 4u)      { KZ = 28; part = tail; }
    else if (ws_size >= (base_f + 14u * 262144u) * 4u) { KZ = 14; part = tail; }
    else                                               { KZ = 7;  part = p1; }   // p1 dead after k2
    const int kchunk = 3136 / KZ;                       // 112 / 224 / 448, all %16==0

    k1_conv1_pool<<<dim3(BATCH), 256, 0, stream>>>(x, W1, root1, b1v, p1);
    k2_conv2_pool<<<dim3(BATCH), 256, 0, stream>>>(p1, W2, root2, b2v, p2);
    k3a_fc1<<<dim3(4, 4, KZ), 256, 0, stream>>>(p2, fc1w, part, kchunk);
    k34_reduce_fc2_lsm<<<dim3(BATCH), 256, 0, stream>>>(part, fc1b, fc2w, fc2b, (float*)d_out, KZ);
}

// Round 7
// 128.907 us; speedup vs baseline: 1.0371x; 1.0371x over previous
//
#include <hip/hip_runtime.h>
#include <math.h>

#define BATCH 512

__device__ __forceinline__ float elu1(float v) {
    return v > 0.f ? v : expm1f(v);
}

// ============ Kernel 1: conv1 (9-dir stencil, 1->32) + ELU + 2x2 pool ============
__global__ __launch_bounds__(256) void k1_conv1_pool(
    const float* __restrict__ x, const float* __restrict__ W1,
    const float* __restrict__ root1, const float* __restrict__ b1,
    float* __restrict__ p1) {
    __shared__ float xs[900];            // [30][30] zero-padded image
    __shared__ float w1s[8 * 32 + 64];
    const int b = blockIdx.x;
    const int t = threadIdx.x;

    for (int l = t; l < 900; l += 256) xs[l] = 0.f;
    {
        int d = t >> 5, c = t & 31;
        int e = d + (d >= 4 ? 1 : 0);
        int dy = e / 3 - 1, dx = e % 3 - 1;
        int widx = 2 * (dx + 1) + 10 * (dy + 1);
        w1s[t] = W1[widx * 32 + c];
        if (t < 32) { w1s[256 + t] = root1[t]; w1s[288 + t] = b1[t]; }
    }
    __syncthreads();
    const float* xb = x + (size_t)b * 784;
    for (int l = t; l < 784; l += 256) {
        int y = l / 28, xx = l % 28;
        xs[(y + 1) * 30 + xx + 1] = xb[l];
    }
    __syncthreads();

    if (t >= 196) return;
    int py = t / 14, px = t % 14;
    int xbse[4];
    float xc[4], inv[4];
    #pragma unroll
    for (int p = 0; p < 4; ++p) {
        int sy = p >> 1, sx = p & 1;
        int y = 2 * py + sy, xx = 2 * px + sx;
        xbse[p] = (y + 1) * 30 + xx + 1;
        xc[p] = xs[xbse[p]];
        int nvy = 3 - (y == 0) - (y == 27);
        int nvx = 3 - (xx == 0) - (xx == 27);
        inv[p] = 1.f / (float)(nvy * nvx - 1);
    }
    const float4* w4 = (const float4*)w1s;
    float* outp = p1 + ((size_t)b * 196 + t) * 32;

    #pragma unroll
    for (int h = 0; h < 2; ++h) {
        float4 acc[4][4];
        #pragma unroll
        for (int p = 0; p < 4; ++p)
            #pragma unroll
            for (int q = 0; q < 4; ++q) acc[p][q] = make_float4(0.f, 0.f, 0.f, 0.f);
        #pragma unroll
        for (int d = 0; d < 8; ++d) {
            int e = d + (d >= 4 ? 1 : 0);
            int od = (e / 3 - 1) * 30 + (e % 3 - 1);
            float4 w0 = w4[d * 8 + h * 4 + 0];
            float4 w1 = w4[d * 8 + h * 4 + 1];
            float4 w2 = w4[d * 8 + h * 4 + 2];
            float4 w3 = w4[d * 8 + h * 4 + 3];
            #pragma unroll
            for (int p = 0; p < 4; ++p) {
                float xv = xs[xbse[p] + od];
                acc[p][0].x += xv * w0.x; acc[p][0].y += xv * w0.y; acc[p][0].z += xv * w0.z; acc[p][0].w += xv * w0.w;
                acc[p][1].x += xv * w1.x; acc[p][1].y += xv * w1.y; acc[p][1].z += xv * w1.z; acc[p][1].w += xv * w1.w;
                acc[p][2].x += xv * w2.x; acc[p][2].y += xv * w2.y; acc[p][2].z += xv * w2.z; acc[p][2].w += xv * w2.w;
                acc[p][3].x += xv * w3.x; acc[p][3].y += xv * w3.y; acc[p][3].z += xv * w3.z; acc[p][3].w += xv * w3.w;
            }
        }
        #pragma unroll
        for (int q = 0; q < 4; ++q) {
            float4 rt = w4[64 + h * 4 + q];
            float4 bs = w4[72 + h * 4 + q];
            float4 m = make_float4(-1e30f, -1e30f, -1e30f, -1e30f);
            #pragma unroll
            for (int p = 0; p < 4; ++p) {
                float4 v;
                v.x = elu1(acc[p][q].x * inv[p] + xc[p] * rt.x + bs.x);
                v.y = elu1(acc[p][q].y * inv[p] + xc[p] * rt.y + bs.y);
                v.z = elu1(acc[p][q].z * inv[p] + xc[p] * rt.z + bs.z);
                v.w = elu1(acc[p][q].w * inv[p] + xc[p] * rt.w + bs.w);
                m.x = fmaxf(m.x, v.x); m.y = fmaxf(m.y, v.y);
                m.z = fmaxf(m.z, v.z); m.w = fmaxf(m.w, v.w);
            }
            *(float4*)(outp + h * 16 + q * 4) = m;
        }
    }
}

// ============ Kernel 2: conv2 (9-dir, 32->64) + ELU + 2x2 pool ============
// CHANNEL-SPLIT: block = (image, half of 64 out-ch). Grid 1024, LDS 45KB -> 3 blocks/CU.
// Same d-outer / i-ascending order as r3/r6 (bit-exact vs np).
__global__ __launch_bounds__(256) void k2_conv2_pool(
    const float* __restrict__ p1, const float* __restrict__ W2,
    const float* __restrict__ root2, const float* __restrict__ b2,
    float* __restrict__ p2) {
    __shared__ float xs[9216];          // 256 nodes * 36, i4-swizzled
    __shared__ float wb[2][1152];       // [32 rows][36], one 32-ch half per direction
    const int b = blockIdx.x >> 1, h = blockIdx.x & 1;
    const int t = threadIdx.x;
    const int cell = t >> 2, cg = t & 3;        // 4 ch-groups of 8
    const int coff = cg * 8;

    static const int widx_t[8] = {0, 2, 4, 10, 14, 20, 22, 24};

    // W staging role: row wi (0..31), f4-chunk wc8 (0..7) of this half's 32 cols
    const int wi = t >> 3, wc8 = t & 7;
    const size_t wsrc = (size_t)wi * 64 + h * 32 + wc8 * 4;
    {
        float4 v = *(const float4*)(W2 + wsrc);   // widx 0 = dir 0
        *(float4*)(wb[0] + wi * 36 + wc8 * 4) = v;
    }
    for (int l = t; l < 9216; l += 256) xs[l] = 0.f;
    __syncthreads();
    // interior fill: channel-major-ish swizzled scatter (same as r6)
    {
        const float* src = p1 + (size_t)b * 6272;
        for (int l = t; l < 6272; l += 256) {
            int node = l >> 5, i = l & 31;
            int y = node / 14, xx = node - y * 14;
            int np = (y + 1) * 16 + xx + 1;
            xs[np * 36 + 4 * ((i >> 2) ^ ((np >> 4) & 7)) + (i & 3)] = src[l];
        }
    }
    __syncthreads();

    const int ccell = (cell < 49) ? cell : 48;
    const int py = ccell / 7, px = ccell - py * 7;
    int npv[4];
    float inv[4];
    #pragma unroll
    for (int p = 0; p < 4; ++p) {
        int sy = p >> 1, sx = p & 1;
        int y = 2 * py + sy, xx = 2 * px + sx;
        npv[p] = (y + 1) * 16 + xx + 1;
        int nvy = 3 - (y == 0) - (y == 13);
        int nvx = 3 - (xx == 0) - (xx == 13);
        inv[p] = 1.f / (float)(nvy * nvx - 1);
    }

    float4 acc[4][2];
    #pragma unroll
    for (int p = 0; p < 4; ++p) { acc[p][0] = make_float4(0,0,0,0); acc[p][1] = make_float4(0,0,0,0); }

    for (int d = 0; d < 9; ++d) {
        float4 pf;
        if (d < 8) {
            int nd = d + 1;
            const float* nsrc = (nd == 8) ? root2 : (W2 + (size_t)widx_t[nd] * 2048);
            pf = *(const float4*)(nsrc + wsrc);
        }
        if (d == 8) {
            #pragma unroll
            for (int p = 0; p < 4; ++p) {
                acc[p][0].x *= inv[p]; acc[p][0].y *= inv[p]; acc[p][0].z *= inv[p]; acc[p][0].w *= inv[p];
                acc[p][1].x *= inv[p]; acc[p][1].y *= inv[p]; acc[p][1].z *= inv[p]; acc[p][1].w *= inv[p];
            }
        }
        int dnode = 0;
        if (d < 8) {
            int e = d + (d >= 4 ? 1 : 0);
            dnode = (e / 3 - 1) * 16 + (e % 3 - 1);
        }
        int xb0, xb1, xb2, xb3, sz0, sz1, sz2, sz3;
        {
            int n0 = npv[0] + dnode, n1 = npv[1] + dnode,
                n2 = npv[2] + dnode, n3 = npv[3] + dnode;
            xb0 = n0 * 36; sz0 = (n0 >> 4) & 7;
            xb1 = n1 * 36; sz1 = (n1 >> 4) & 7;
            xb2 = n2 * 36; sz2 = (n2 >> 4) & 7;
            xb3 = n3 * 36; sz3 = (n3 >> 4) & 7;
        }
        const float* wcur = wb[d & 1] + coff;
        #pragma unroll 2
        for (int i4 = 0; i4 < 8; ++i4) {
            float4 xv0 = *(const float4*)(xs + xb0 + 4 * (i4 ^ sz0));
            float4 xv1 = *(const float4*)(xs + xb1 + 4 * (i4 ^ sz1));
            float4 xv2 = *(const float4*)(xs + xb2 + 4 * (i4 ^ sz2));
            float4 xv3 = *(const float4*)(xs + xb3 + 4 * (i4 ^ sz3));
            float xa0[4] = {xv0.x, xv0.y, xv0.z, xv0.w};
            float xa1[4] = {xv1.x, xv1.y, xv1.z, xv1.w};
            float xa2[4] = {xv2.x, xv2.y, xv2.z, xv2.w};
            float xa3[4] = {xv3.x, xv3.y, xv3.z, xv3.w};
            #pragma unroll
            for (int ii = 0; ii < 4; ++ii) {
                const float* wrow = wcur + (i4 * 4 + ii) * 36;
                float4 w0 = *(const float4*)(wrow + 0);
                float4 w1 = *(const float4*)(wrow + 4);
                float x0 = xa0[ii], x1 = xa1[ii], x2 = xa2[ii], x3 = xa3[ii];
                acc[0][0].x += x0 * w0.x; acc[0][0].y += x0 * w0.y; acc[0][0].z += x0 * w0.z; acc[0][0].w += x0 * w0.w;
                acc[0][1].x += x0 * w1.x; acc[0][1].y += x0 * w1.y; acc[0][1].z += x0 * w1.z; acc[0][1].w += x0 * w1.w;
                acc[1][0].x += x1 * w0.x; acc[1][0].y += x1 * w0.y; acc[1][0].z += x1 * w0.z; acc[1][0].w += x1 * w0.w;
                acc[1][1].x += x1 * w1.x; acc[1][1].y += x1 * w1.y; acc[1][1].z += x1 * w1.z; acc[1][1].w += x1 * w1.w;
                acc[2][0].x += x2 * w0.x; acc[2][0].y += x2 * w0.y; acc[2][0].z += x2 * w0.z; acc[2][0].w += x2 * w0.w;
                acc[2][1].x += x2 * w1.x; acc[2][1].y += x2 * w1.y; acc[2][1].z += x2 * w1.z; acc[2][1].w += x2 * w1.w;
                acc[3][0].x += x3 * w0.x; acc[3][0].y += x3 * w0.y; acc[3][0].z += x3 * w0.z; acc[3][0].w += x3 * w0.w;
                acc[3][1].x += x3 * w1.x; acc[3][1].y += x3 * w1.y; acc[3][1].z += x3 * w1.z; acc[3][1].w += x3 * w1.w;
            }
        }
        if (d < 8) {
            *(float4*)(wb[(d + 1) & 1] + wi * 36 + wc8 * 4) = pf;
        }
        __syncthreads();
    }

    if (cell < 49) {
        float* outp = p2 + (size_t)b * 3136 + cell * 64 + h * 32 + cg * 8;
        #pragma unroll
        for (int q = 0; q < 2; ++q) {
            float4 bs = *(const float4*)(b2 + h * 32 + cg * 8 + q * 4);
            float4 m = make_float4(-1e30f, -1e30f, -1e30f, -1e30f);
            #pragma unroll
            for (int p = 0; p < 4; ++p) {
                float4 v;
                v.x = elu1(acc[p][q].x + bs.x);
                v.y = elu1(acc[p][q].y + bs.y);
                v.z = elu1(acc[p][q].z + bs.z);
                v.w = elu1(acc[p][q].w + bs.w);
                m.x = fmaxf(m.x, v.x); m.y = fmaxf(m.y, v.y);
                m.z = fmaxf(m.z, v.z); m.w = fmaxf(m.w, v.w);
            }
            *(float4*)(outp + q * 4) = m;
        }
    }
}

// ============ Kernel 3a: fc1 split-K GEMM, 64x64 tile, 4x4/thread, BK=16, KZ=12 ============
// part aliases p1 (12*512*512 = 3.15M floats <= p1's 3.21M) -> no ws_size dependence.
// k-chunks: 11 x 272 + 1 x 144 (all mult of 16).
__global__ __launch_bounds__(256) void k3a_fc1(
    const float* __restrict__ A, const float* __restrict__ B,
    float* __restrict__ part) {
    __shared__ float As[2][16][64];
    __shared__ float Bs[2][16][72];
    const int t = threadIdx.x;
    const int tx = t & 15, ty = t >> 4;
    const int n0 = blockIdx.x * 64, m0 = blockIdx.y * 64;
    const int k0 = blockIdx.z * 272;
    const int steps = ((blockIdx.z == 11) ? 144 : 272) >> 4;

    const int sm = t & 63, k4 = t >> 6;       // A staging: row, 4-float chunk
    const int sk = t >> 4, sc = t & 15;       // B staging: k-row, col-f4
    const float* Ap = A + (size_t)(m0 + sm) * 3136 + k0 + k4 * 4;
    const float* Bp = B + (size_t)(k0 + sk) * 512 + n0 + sc * 4;

    {
        float4 av = *(const float4*)Ap;
        float4 bv = *(const float4*)Bp;
        As[0][k4 * 4 + 0][sm] = av.x; As[0][k4 * 4 + 1][sm] = av.y;
        As[0][k4 * 4 + 2][sm] = av.z; As[0][k4 * 4 + 3][sm] = av.w;
        *(float4*)&Bs[0][sk][sc * 4] = bv;
    }
    __syncthreads();

    float acc[4][4];
    #pragma unroll
    for (int r = 0; r < 4; ++r)
        #pragma unroll
        for (int c = 0; c < 4; ++c) acc[r][c] = 0.f;

    for (int s = 0; s < steps; ++s) {
        float4 a0, b0;
        if (s + 1 < steps) {
            a0 = *(const float4*)(Ap + (s + 1) * 16);
            b0 = *(const float4*)(Bp + (size_t)(s + 1) * 16 * 512);
        }
        const int cur = s & 1;
        #pragma unroll
        for (int k = 0; k < 16; ++k) {
            float4 a4 = *(const float4*)&As[cur][k][ty * 4];
            float4 b4 = *(const float4*)&Bs[cur][k][tx * 4];
            acc[0][0] += a4.x * b4.x; acc[0][1] += a4.x * b4.y; acc[0][2] += a4.x * b4.z; acc[0][3] += a4.x * b4.w;
            acc[1][0] += a4.y * b4.x; acc[1][1] += a4.y * b4.y; acc[1][2] += a4.y * b4.z; acc[1][3] += a4.y * b4.w;
            acc[2][0] += a4.z * b4.x; acc[2][1] += a4.z * b4.y; acc[2][2] += a4.z * b4.z; acc[2][3] += a4.z * b4.w;
            acc[3][0] += a4.w * b4.x; acc[3][1] += a4.w * b4.y; acc[3][2] += a4.w * b4.z; acc[3][3] += a4.w * b4.w;
        }
        if (s + 1 < steps) {
            const int nxt = cur ^ 1;
            As[nxt][k4 * 4 + 0][sm] = a0.x; As[nxt][k4 * 4 + 1][sm] = a0.y;
            As[nxt][k4 * 4 + 2][sm] = a0.z; As[nxt][k4 * 4 + 3][sm] = a0.w;
            *(float4*)&Bs[nxt][sk][sc * 4] = b0;
        }
        __syncthreads();
    }

    float* pbase = part + ((size_t)blockIdx.z * 512 + m0 + ty * 4) * 512 + n0;
    #pragma unroll
    for (int r = 0; r < 4; ++r)
        *(float4*)(pbase + (size_t)r * 512 + tx * 4) =
            make_float4(acc[r][0], acc[r][1], acc[r][2], acc[r][3]);
}

// ============ Kernel 34: reduce fc1 partials + bias + ELU, then fc2 + ELU + lsm ============
__global__ __launch_bounds__(256) void k34_reduce_fc2_lsm(
    const float* __restrict__ part, const float* __restrict__ fc1b,
    const float* __restrict__ w, const float* __restrict__ fc2b,
    float* __restrict__ out, int KZ) {
    __shared__ float red[4][10];
    const int b = blockIdx.x, t = threadIdx.x;

    float a0 = fc1b[t], a1 = fc1b[t + 256];
    for (int kz = 0; kz < KZ; ++kz) {
        const float* pr = part + ((size_t)kz * 512 + b) * 512;
        a0 += pr[t]; a1 += pr[t + 256];
    }
    a0 = elu1(a0); a1 = elu1(a1);

    float acc[10];
    #pragma unroll
    for (int o = 0; o < 10; ++o)
        acc[o] = a0 * w[t * 10 + o] + a1 * w[(t + 256) * 10 + o];
    #pragma unroll
    for (int s = 32; s; s >>= 1)
        #pragma unroll
        for (int o = 0; o < 10; ++o) acc[o] += __shfl_xor(acc[o], s, 64);
    if ((t & 63) == 0) {
        #pragma unroll
        for (int o = 0; o < 10; ++o) red[t >> 6][o] = acc[o];
    }
    __syncthreads();
    if (t == 0) {
        float v[10], m = -1e30f;
        #pragma unroll
        for (int o = 0; o < 10; ++o) {
            float s = red[0][o] + red[1][o] + red[2][o] + red[3][o] + fc2b[o];
            v[o] = elu1(s);
            m = fmaxf(m, v[o]);
        }
        float ssum = 0.f;
        #pragma unroll
        for (int o = 0; o < 10; ++o) ssum += expf(v[o] - m);
        float lse = m + logf(ssum);
        #pragma unroll
        for (int o = 0; o < 10; ++o) out[(size_t)b * 10 + o] = v[o] - lse;
    }
}

extern "C" void kernel_launch(void* const* d_in, const int* in_sizes, int n_in,
                              void* d_out, int out_size, void* d_ws, size_t ws_size,
                              hipStream_t stream) {
    const float* x     = (const float*)d_in[0];
    const float* W1    = (const float*)d_in[3];
    const float* root1 = (const float*)d_in[4];
    const float* b1v   = (const float*)d_in[5];
    const float* W2    = (const float*)d_in[6];
    const float* root2 = (const float*)d_in[7];
    const float* b2v   = (const float*)d_in[8];
    const float* fc1w  = (const float*)d_in[9];
    const float* fc1b  = (const float*)d_in[10];
    const float* fc2w  = (const float*)d_in[11];
    const float* fc2b  = (const float*)d_in[12];

    float* ws = (float*)d_ws;
    float* p1 = ws;                                   // 3,211,264 f
    float* p2 = p1 + (size_t)BATCH * 196 * 32;        // 1,605,632 f
    float* part = p1;                                 // p1 dead after k2; 12*262144 = 3,145,728 f fits

    k1_conv1_pool<<<dim3(BATCH), 256, 0, stream>>>(x, W1, root1, b1v, p1);
    k2_conv2_pool<<<dim3(2 * BATCH), 256, 0, stream>>>(p1, W2, root2, b2v, p2);
    k3a_fc1<<<dim3(8, 8, 12), 256, 0, stream>>>(p2, fc1w, part);
    k34_reduce_fc2_lsm<<<dim3(BATCH), 256, 0, stream>>>(part, fc1b, fc2w, fc2b, (float*)d_out, 12);
}